// Round 4
// baseline (68.085 us; speedup 1.0000x reference)
//
#include <hip/hip_runtime.h>

typedef float f4 __attribute__((ext_vector_type(4)));

#define BB 32
#define CC 512
#define LL 4096
#define NB 16
#define EPSF 1e-8f

// ---------------- fused main kernel: g + partial dot/ss, ONE read of x ----
// grid = 32 b x 16 chunks = 512 blocks (2/CU, 64KB LDS). chunk = 32 channels,
// 8 stages x 4 rows. Per stage: wave w loads row w (16 f4/lane, NT) ->
// row-sum in regs (g) -> spill to LDS -> issue next stage's NT loads ->
// dot/ss pass from LDS (ds_read_b128) into float4 accumulators.
// Thread t owns l = 1024j + 4t + k  (j=0..3, k=0..3) -> flat partial layout
// is identity in l (float4 slot 256j+t covers l=1024j+4t..+3).
__global__ __launch_bounds__(256, 2)
void k_main(const float* __restrict__ x, float* __restrict__ g,
            f4* __restrict__ pd4, f4* __restrict__ ps4) {
    __shared__ float lds[4 * LL];          // 64 KB
    __shared__ float sgv[4];
    const int tid = threadIdx.x;
    const int w = tid >> 6, lane = tid & 63;
    const int b  = blockIdx.x >> 4;
    const int c0 = (blockIdx.x & 15) * 32;
    const f4* xr = (const f4*)(x + ((size_t)b * CC + c0 + w) * LL);  // wave w stage-0 row

    f4 d4[4], s4[4];
#pragma unroll
    for (int j = 0; j < 4; ++j) { d4[j] = (f4)0.f; s4[j] = (f4)0.f; }

    f4 v[16];
#pragma unroll
    for (int i = 0; i < 16; ++i) v[i] = __builtin_nontemporal_load(&xr[i * 64 + lane]);

    for (int st = 0; st < 8; ++st) {
        // row sum (from regs) -> g
        float s = 0.f;
#pragma unroll
        for (int i = 0; i < 16; ++i) s += (v[i][0] + v[i][1]) + (v[i][2] + v[i][3]);
#pragma unroll
        for (int off = 32; off; off >>= 1) s += __shfl_down(s, off, 64);
        __syncthreads();                    // prev stage's LDS/sgv readers done
        if (lane == 0) {
            float gv = s * (1.0f / LL);
            sgv[w] = gv;
            g[b * CC + c0 + st * 4 + w] = gv;
        }
        f4* lrow = (f4*)&lds[w * LL];
#pragma unroll
        for (int i = 0; i < 16; ++i) lrow[i * 64 + lane] = v[i];
        __syncthreads();                    // LDS + sgv visible
        // issue next stage's global loads BEFORE the dot pass (pipeline)
        if (st < 7) {
            const f4* nxt = xr + (size_t)(st + 1) * 4096;   // 4 rows * 1024 f4
#pragma unroll
            for (int i = 0; i < 16; ++i) v[i] = __builtin_nontemporal_load(&nxt[i * 64 + lane]);
        }
        // dot/ss pass: 16 ds_read_b128 per stage, conflict-free
#pragma unroll
        for (int c = 0; c < 4; ++c) {
            const float gv = sgv[c];
            const f4* lc4 = (const f4*)&lds[c * LL];
#pragma unroll
            for (int j = 0; j < 4; ++j) {
                f4 f = lc4[j * 256 + tid];
#pragma unroll
                for (int k = 0; k < 4; ++k) {
                    d4[j][k] = fmaf(f[k], gv, d4[j][k]);
                    s4[j][k] = fmaf(f[k], f[k], s4[j][k]);
                }
            }
        }
    }
#pragma unroll
    for (int j = 0; j < 4; ++j) {
        pd4[(size_t)blockIdx.x * 1024 + j * 256 + tid] = d4[j];
        ps4[(size_t)blockIdx.x * 1024 + j * 256 + tid] = s4[j];
    }
}

// ---------------- reduce: fold chunk partials -> cos + min/max partials ----
// 256 blocks (b x 8) x 128 threads; thread owns one l-quad (float4).
__global__ void k_reduce(const float* __restrict__ g,
                         const f4* __restrict__ pd4, const f4* __restrict__ ps4,
                         f4* __restrict__ cosv4,
                         float* __restrict__ pmin, float* __restrict__ pmax) {
    const int tid = threadIdx.x;            // 0..127
    const int w = tid >> 6, lane = tid & 63;
    const int b = blockIdx.x >> 3;
    const int q = blockIdx.x & 7;
    const int s = q * 128 + tid;            // quad slot in [0,1024)

    // gn = sqrt(sum_c g^2) (block-redundant, L2-hot)
    f4 g4 = ((const f4*)g)[b * 128 + tid];
    float sq = fmaf(g4[0], g4[0], fmaf(g4[1], g4[1], fmaf(g4[2], g4[2], g4[3] * g4[3])));
#pragma unroll
    for (int off = 32; off; off >>= 1) sq += __shfl_down(sq, off, 64);
    __shared__ float sw[2];
    if (lane == 0) sw[w] = sq;
    __syncthreads();
    const float gn = sqrtf(sw[0] + sw[1]);

    f4 pdv = (f4)0.f, psv = (f4)0.f;
#pragma unroll
    for (int ch = 0; ch < 16; ++ch) {
        pdv += pd4[(((size_t)b * 16 + ch) << 10) + s];
        psv += ps4[(((size_t)b * 16 + ch) << 10) + s];
    }
    f4 cs;
#pragma unroll
    for (int k = 0; k < 4; ++k)
        cs[k] = pdv[k] / fmaxf(sqrtf(psv[k]) * gn, EPSF);
    cosv4[(size_t)b * 1024 + s] = cs;

    float mn = fminf(fminf(cs[0], cs[1]), fminf(cs[2], cs[3]));
    float mx = fmaxf(fmaxf(cs[0], cs[1]), fmaxf(cs[2], cs[3]));
#pragma unroll
    for (int off = 32; off; off >>= 1) {
        mn = fminf(mn, __shfl_down(mn, off, 64));
        mx = fmaxf(mx, __shfl_down(mx, off, 64));
    }
    __shared__ float smn[2], smx[2];
    if (lane == 0) { smn[w] = mn; smx[w] = mx; }
    __syncthreads();
    if (tid == 0) {
        pmin[blockIdx.x] = fminf(smn[0], smn[1]);
        pmax[blockIdx.x] = fmaxf(smx[0], smx[1]);
    }
}

// ---------------- histogram per b, normalize, broadcast ----------------
__global__ void k_hist(const float* __restrict__ cosv,
                       const float* __restrict__ pmin, const float* __restrict__ pmax,
                       float* __restrict__ out) {
    const int b = blockIdx.x;
    const int wave = threadIdx.x >> 6, lane = threadIdx.x & 63;

    float mn = pmin[threadIdx.x];           // 256 partials, one per thread
    float mx = pmax[threadIdx.x];
#pragma unroll
    for (int off = 32; off; off >>= 1) {
        mn = fminf(mn, __shfl_down(mn, off, 64));
        mx = fmaxf(mx, __shfl_down(mx, off, 64));
    }
    __shared__ float smn[4], smx[4];
    if (lane == 0) { smn[wave] = mn; smx[wave] = mx; }
    __syncthreads();
    mn = fminf(fminf(smn[0], smn[1]), fminf(smn[2], smn[3]));
    mx = fmaxf(fmaxf(smx[0], smx[1]), fmaxf(smx[2], smx[3]));
    const float range = mx - mn;

    float bins[NB];
#pragma unroll
    for (int n = 0; n < NB; ++n) bins[n] = 0.f;

    const float* cb = cosv + (b << 12);
    for (int l = threadIdx.x; l < LL; l += 256) {
        float s = cb[l];
#pragma unroll
        for (int n = 0; n < NB; ++n) {
            float lev = mn + ((float)n * range) / 15.0f;   // match ref order of ops
            float d = fabsf(s - lev);
            bins[n] += (d < 0.03125f) ? (1.0f - d) : 0.f;
        }
    }
#pragma unroll
    for (int n = 0; n < NB; ++n) {
#pragma unroll
        for (int off = 32; off; off >>= 1) bins[n] += __shfl_down(bins[n], off, 64);
    }
    __shared__ float sb[4][NB];
    if (lane == 0) {
#pragma unroll
        for (int n = 0; n < NB; ++n) sb[wave][n] = bins[n];
    }
    __syncthreads();
    __shared__ float colsum[NB];
    if (threadIdx.x < NB) {
        const int n = threadIdx.x;
        colsum[n] = sb[0][n] + sb[1][n] + sb[2][n] + sb[3][n];
    }
    __syncthreads();
    float total = 0.f;
#pragma unroll
    for (int n = 0; n < NB; ++n) total += colsum[n];
    {
        const int i0 = threadIdx.x;
        out[b * (NB * 32) + i0]       = colsum[i0 >> 5] / total;
        out[b * (NB * 32) + i0 + 256] = colsum[(i0 + 256) >> 5] / total;
    }
}

extern "C" void kernel_launch(void* const* d_in, const int* in_sizes, int n_in,
                              void* d_out, int out_size, void* d_ws, size_t ws_size,
                              hipStream_t stream) {
    const float* x = (const float*)d_in[0];
    float* out = (float*)d_out;
    float* ws  = (float*)d_ws;

    float* g    = ws;                      // 16384 floats
    float* cosv = ws + 16384;              // 131072 floats
    float* pmin = ws + 16384 + 131072;     // 256
    float* pmax = pmin + 256;              // 256
    f4*    pd4  = (f4*)(pmax + 256);       // 512 blocks * 1024 f4 = 2M floats
    f4*    ps4  = pd4 + 524288;            // 2M floats

    k_main<<<512, 256, 0, stream>>>(x, g, pd4, ps4);
    k_reduce<<<256, 128, 0, stream>>>(g, pd4, ps4, (f4*)cosv, pmin, pmax);
    k_hist<<<32, 256, 0, stream>>>(cosv, pmin, pmax, out);
}